// Round 14
// baseline (60.892 us; speedup 1.0000x reference)
//
#include <hip/hip_runtime.h>
#include <math.h>

#define LQ 1024
#define BB 8
#define FF 256
#define HH 8
#define CC 32
#define MROWS (LQ*BB)          // 8192
static constexpr float EPSV  = 1e-5f;
static constexpr float LOG2E = 1.4426950408889634f;
static constexpr float C1    = 0.17677669529663687f * 1.4426950408889634f; // (1/sqrt C)*log2e

typedef short  short8  __attribute__((ext_vector_type(8)));
typedef short  short4v __attribute__((ext_vector_type(4)));
typedef float  float4v __attribute__((ext_vector_type(4)));

__device__ inline unsigned short f2bf(float f) {   // RNE float->bf16
    unsigned int u = __builtin_bit_cast(unsigned int, f);
    u += 0x7FFFu + ((u >> 16) & 1u);
    return (unsigned short)(u >> 16);
}
__device__ inline float bf2f(unsigned short h) {
    unsigned int u = ((unsigned int)h) << 16;
    return __builtin_bit_cast(float, u);
}
__device__ inline unsigned int cvt_pk_bf16(float a, float b) {  // a->low16, b->high16
    unsigned int r;
    asm("v_cvt_pk_bf16_f32 %0, %1, %2" : "=v"(r) : "v"(a), "v"(b));
    return r;
}
// async global->LDS, 16B per lane; LDS dest = wave-uniform base + lane*16
__device__ __forceinline__ void gl_lds16(const unsigned short* g, unsigned short* l) {
    __builtin_amdgcn_global_load_lds(
        (const __attribute__((address_space(1))) void*)g,
        (__attribute__((address_space(3))) void*)l, 16, 0, 0);
}

// ---------------------------------------------------------------------------
// Fused prep: blocks 0..2047 LayerNorm+bf16 cast (4 rows each);
// blocks 2048..2111 transpose+cast weights; block 2112 transposes Wb.
__global__ __launch_bounds__(256)
void prep_ln_kernel(const float* __restrict__ x, const float* __restrict__ g,
                    const float* __restrict__ bln,
                    const float* __restrict__ Wq, const float* __restrict__ Wk,
                    const float* __restrict__ Wv, const float* __restrict__ Wg,
                    const float* __restrict__ Wo, const float* __restrict__ Wb,
                    const float* __restrict__ bq, const float* __restrict__ bk,
                    const float* __restrict__ bv, const float* __restrict__ bg,
                    unsigned short* __restrict__ xb, unsigned short* __restrict__ wt,
                    unsigned short* __restrict__ wto,
                    float* __restrict__ bcomb, float* __restrict__ wbt) {
    int bid = blockIdx.x;
    if (bid < 2048) {                      // LayerNorm path
        int wid  = threadIdx.x >> 6;
        int lane = threadIdx.x & 63;
        int row  = bid * 4 + wid;
        float4 v = reinterpret_cast<const float4*>(x + (size_t)row * FF)[lane];
        float s  = v.x + v.y + v.z + v.w;
        float sq = v.x*v.x + v.y*v.y + v.z*v.z + v.w*v.w;
        #pragma unroll
        for (int m = 1; m < 64; m <<= 1) {
            s  += __shfl_xor(s,  m);
            sq += __shfl_xor(sq, m);
        }
        float mean = s * (1.0f / FF);
        float var  = sq * (1.0f / FF) - mean * mean;
        float rstd = rsqrtf(var + EPSV);
        float4 gg = reinterpret_cast<const float4*>(g)[lane];
        float4 bv4 = reinterpret_cast<const float4*>(bln)[lane];
        short4v o;
        o[0] = (short)f2bf((v.x - mean) * rstd * gg.x + bv4.x);
        o[1] = (short)f2bf((v.y - mean) * rstd * gg.y + bv4.y);
        o[2] = (short)f2bf((v.z - mean) * rstd * gg.z + bv4.z);
        o[3] = (short)f2bf((v.w - mean) * rstd * gg.w + bv4.w);
        *reinterpret_cast<short4v*>(xb + (size_t)row * FF + lane * 4) = o;
    } else if (bid < 2112) {               // weight transpose path
        int k0 = (bid - 2048) * 4;
        int nl = threadIdx.x;
        const float* Ws[5] = {Wq, Wk, Wv, Wg, Wo};
        #pragma unroll
        for (int sel = 0; sel < 5; ++sel) {
            const float* W = Ws[sel];
            short4v o;
            #pragma unroll
            for (int j = 0; j < 4; ++j)
                o[j] = (short)f2bf(W[(size_t)(k0 + j) * 256 + nl]);
            unsigned short* dst = (sel < 4)
                ? (wt + ((size_t)sel * 256 + nl) * 256 + k0)
                : (wto + (size_t)nl * 256 + k0);
            *reinterpret_cast<short4v*>(dst) = o;
        }
        if (k0 == 0) {
            bcomb[nl]       = bq[nl];
            bcomb[256 + nl] = bk[nl];
            bcomb[512 + nl] = bv[nl];
            bcomb[768 + nl] = bg[nl];
        }
    } else {                               // Wb transpose: wbt[8][256] f32
        int nl = threadIdx.x;
        #pragma unroll
        for (int hh = 0; hh < 8; ++hh)
            wbt[hh * 256 + nl] = Wb[(size_t)nl * 8 + hh];
    }
}

// ---------------------------------------------------------------------------
// Fused QKVG projection GEMM (global_load_lds staging, pre-swizzled source)
// + bias projection. Blocks 0..511: GEMM 128x128; 512..767: biasproj.
// biasproj output is pre-scaled by LOG2E (consumed in exp2-domain by attn).
__global__ __launch_bounds__(256)
void qkvg_fused_kernel(const unsigned short* __restrict__ A,
                       const unsigned short* __restrict__ Bt,
                       const float* __restrict__ bcomb,
                       const float* __restrict__ wbt,
                       const float* __restrict__ bbv,
                       unsigned short* __restrict__ outq,
                       float* __restrict__ outb) {
    __shared__ unsigned short Asb[128 * 64];
    __shared__ unsigned short Bsb[128 * 64];
    int bid = blockIdx.x;
    int tid = threadIdx.x;

    if (bid >= 512) {                      // bias projection path
        int idx = (bid - 512) * 256 + tid;
        int row = idx >> 3, hh = idx & 7;
        const unsigned short* xr = A + (size_t)row * 256;
        const float* wr = wbt + hh * 256;
        float s = 0.f;
        #pragma unroll 4
        for (int i = 0; i < 32; ++i) {
            short8 x8 = *reinterpret_cast<const short8*>(xr + i * 8);
            float4 wa = *reinterpret_cast<const float4*>(wr + i * 8);
            float4 wb2 = *reinterpret_cast<const float4*>(wr + i * 8 + 4);
            s += bf2f((unsigned short)x8[0]) * wa.x + bf2f((unsigned short)x8[1]) * wa.y
               + bf2f((unsigned short)x8[2]) * wa.z + bf2f((unsigned short)x8[3]) * wa.w;
            s += bf2f((unsigned short)x8[4]) * wb2.x + bf2f((unsigned short)x8[5]) * wb2.y
               + bf2f((unsigned short)x8[6]) * wb2.z + bf2f((unsigned short)x8[7]) * wb2.w;
        }
        outb[idx] = (s + bbv[hh]) * LOG2E;
        return;
    }

    int lane = tid & 63;
    int w    = tid >> 6;
    int wm   = w >> 1, wn = w & 1;
    int l15  = lane & 15, lg = lane >> 4;
    int bm   = (bid & 63) * 128;
    int bn   = (bid >> 6) * 128;

    float4v acc[4][4];
    #pragma unroll
    for (int i = 0; i < 4; ++i)
        #pragma unroll
        for (int j = 0; j < 4; ++j)
            acc[i][j] = (float4v){0.f, 0.f, 0.f, 0.f};

    for (int k0 = 0; k0 < 256; k0 += 64) {
        __syncthreads();
        // each wave stages 4 chunks of A and 4 of B (chunk = 64 units = 1KB)
        #pragma unroll
        for (int j = 0; j < 4; ++j) {
            int c = w * 4 + j;
            int u = c * 64 + lane;
            int row = u >> 3, slot = u & 7;
            size_t gsw = (size_t)row * 256 + k0 + ((slot ^ (row & 7)) * 8);
            gl_lds16(A + (size_t)bm * 256 + gsw, Asb + c * 512);
            gl_lds16(Bt + (size_t)bn * 256 + gsw, Bsb + c * 512);
        }
        __syncthreads();
        #pragma unroll
        for (int kh = 0; kh < 2; ++kh) {
            int slot = kh * 4 + lg;
            short8 af[4], bf[4];
            #pragma unroll
            for (int mf = 0; mf < 4; ++mf) {
                int row = wm * 64 + mf * 16 + l15;
                af[mf] = *reinterpret_cast<const short8*>(
                    Asb + row * 64 + ((slot ^ (row & 7)) * 8));
            }
            #pragma unroll
            for (int nf = 0; nf < 4; ++nf) {
                int row = wn * 64 + nf * 16 + l15;
                bf[nf] = *reinterpret_cast<const short8*>(
                    Bsb + row * 64 + ((slot ^ (row & 7)) * 8));
            }
            #pragma unroll
            for (int mf = 0; mf < 4; ++mf)
                #pragma unroll
                for (int nf = 0; nf < 4; ++nf)
                    acc[mf][nf] = __builtin_amdgcn_mfma_f32_16x16x32_bf16(
                        bf[nf], af[mf], acc[mf][nf], 0, 0, 0);  // D col = m-row
        }
    }

    int sel = bn >> 8;
    unsigned short* outp = outq + (size_t)sel * MROWS * 256;
    #pragma unroll
    for (int mf = 0; mf < 4; ++mf) {
        int m = bm + wm * 64 + mf * 16 + l15;
        #pragma unroll
        for (int nf = 0; nf < 4; ++nf) {
            int nglob = bn + wn * 64 + nf * 16 + lg * 4;
            float4 b4 = *reinterpret_cast<const float4*>(bcomb + nglob);
            float v0 = acc[mf][nf][0] + b4.x;
            float v1 = acc[mf][nf][1] + b4.y;
            float v2 = acc[mf][nf][2] + b4.z;
            float v3 = acc[mf][nf][3] + b4.w;
            if (sel == 3) {
                v0 = 1.0f / (1.0f + __expf(-v0));
                v1 = 1.0f / (1.0f + __expf(-v1));
                v2 = 1.0f / (1.0f + __expf(-v2));
                v3 = 1.0f / (1.0f + __expf(-v3));
            }
            uint2 st;
            st.x = cvt_pk_bf16(v0, v1);
            st.y = cvt_pk_bf16(v2, v3);
            *reinterpret_cast<uint2*>(outp + (size_t)m * 256 + (nglob & 255)) = st;
        }
    }
}

// ---------------------------------------------------------------------------
// MFMA flash attention + gate, v9 (split-K + double-buffered K/V LDS).
// 512 thr = 8 waves; wave w owns q-group w>>1 (32 rows) and key-half w&1.
// K/V/bias LDS is 2-deep: per chunk = {issue next-chunk global loads ->
// compute current buffer -> write regs into OTHER buffer -> ONE barrier}.
// Barriers per block: 16 -> 9. LDS 69 KB, still 2 blocks/CU (16 waves/CU).
__global__ __launch_bounds__(512)
void attn_mfma_kernel(const unsigned short* __restrict__ qkvg,
                      const float* __restrict__ biasp,
                      unsigned short* __restrict__ ag) {
    __shared__ unsigned short ksl[2][128][40];  // K chunk, stride 40 (2-way free)
    __shared__ unsigned short vt[2][32 * 128];  // V^T, 16-slot xor swizzle
    __shared__ unsigned short ps[8][32 * 64];   // per-wave P (32q x 64keys)
    __shared__ float bias_s[2][128];
    const unsigned short* qb = qkvg;
    const unsigned short* kb = qkvg + (size_t)MROWS * 256;
    const unsigned short* vb = qkvg + (size_t)MROWS * 256 * 2;
    const unsigned short* gb = qkvg + (size_t)MROWS * 256 * 3;

    int tid  = threadIdx.x;
    int lane = tid & 63;
    int w    = tid >> 6;                 // 0..7
    int l15  = lane & 15, lg = lane >> 4;
    int bh   = blockIdx.y;
    int b    = bh >> 3, h = bh & 7;
    int qg   = w >> 1;                   // q-group 0..3 (32 rows each)
    int kh2  = w & 1;                    // key-half 0/1 (64 keys each)
    int qrow0 = blockIdx.x * 128 + qg * 32;

    // staging assignment (all 512 threads stage full K and V^T)
    int krow = tid >> 2, kc8 = (tid & 3) * 8;        // K: 1 16B-unit each
    int cv = (tid & 7) * 4, kp = tid >> 3;           // V: keys 2kp,2kp+1, c cv..cv+3

    short8 qf[2];
    #pragma unroll
    for (int qt = 0; qt < 2; ++qt)
        qf[qt] = *reinterpret_cast<const short8*>(
            qb + ((size_t)(qrow0 + qt * 16 + l15) * 8 + b) * 256 + h * 32 + lg * 8);

    float lsum[2] = {0.f, 0.f};
    float4v oacc[2][2];
    #pragma unroll
    for (int i = 0; i < 2; ++i)
        #pragma unroll
        for (int j = 0; j < 2; ++j) oacc[i][j] = (float4v){0.f, 0.f, 0.f, 0.f};

    short8 kreg; short4v v0r, v1r; float breg = 0.f;
    {   // prefetch chunk 0 -> regs, write buf0, barrier
        kreg = *reinterpret_cast<const short8*>(
            kb + ((size_t)krow * 8 + b) * 256 + h * 32 + kc8);
        const unsigned short* vp =
            vb + ((size_t)(2 * kp) * 8 + b) * 256 + h * 32 + cv;
        v0r = *reinterpret_cast<const short4v*>(vp);
        v1r = *reinterpret_cast<const short4v*>(vp + 8 * 256);
        if (tid < 128) breg = biasp[(size_t)tid * 64 + b * 8 + h];

        *reinterpret_cast<short8*>(&ksl[0][krow][kc8]) = kreg;
        #pragma unroll
        for (int j = 0; j < 4; ++j) {
            int c = cv + j;
            unsigned int pk = (unsigned int)(unsigned short)v0r[j] |
                              ((unsigned int)(unsigned short)v1r[j] << 16);
            int slot = kp >> 2;
            int off  = c * 128 + ((slot ^ (c & 7)) * 8) + ((2 * kp) & 7);
            *reinterpret_cast<unsigned int*>(&vt[0][off]) = pk;
        }
        if (tid < 128) bias_s[0][tid] = breg;
        __syncthreads();
    }

    for (int ci = 0; ci < 8; ++ci) {
        int cur = ci & 1;
        int cn  = (ci + 1) * 128;
        bool more = cn < LQ;
        if (more) {                      // issue next-chunk global loads
            kreg = *reinterpret_cast<const short8*>(
                kb + ((size_t)(cn + krow) * 8 + b) * 256 + h * 32 + kc8);
            const unsigned short* vp =
                vb + ((size_t)(cn + 2 * kp) * 8 + b) * 256 + h * 32 + cv;
            v0r = *reinterpret_cast<const short4v*>(vp);
            v1r = *reinterpret_cast<const short4v*>(vp + 8 * 256);
            if (tid < 128) breg = biasp[(size_t)(cn + tid) * 64 + b * 8 + h];
        }

        // S^T = mfma(K, Q) over this wave's key-half: key = kh2*64 + kt*16 +
        // lg*4 + r, col = q(l15). Each kf feeds both q-tiles (register reuse).
        __builtin_amdgcn_s_setprio(1);
        float4v sc[2][4];
        #pragma unroll
        for (int kt = 0; kt < 4; ++kt) {
            short8 kf = *reinterpret_cast<const short8*>(
                &ksl[cur][kh2 * 64 + kt * 16 + l15][lg * 8]);
            #pragma unroll
            for (int qt = 0; qt < 2; ++qt)
                sc[qt][kt] = __builtin_amdgcn_mfma_f32_16x16x32_bf16(
                    kf, qf[qt], (float4v){0.f, 0.f, 0.f, 0.f}, 0, 0, 0);
        }
        __builtin_amdgcn_s_setprio(0);

        // P = exp2(qk*C1 + bias2), no max subtraction (|logit| small)
        #pragma unroll
        for (int qt = 0; qt < 2; ++qt) {
            int prow = qt * 16 + l15;
            unsigned short* pw = &ps[w][prow * 64];
            int rsw = prow & 7;
            float psum = 0.f;
            #pragma unroll
            for (int kt = 0; kt < 4; ++kt) {
                float4v b4 = *reinterpret_cast<const float4v*>(
                    &bias_s[cur][kh2 * 64 + kt * 16 + lg * 4]);
                float p0 = __builtin_amdgcn_exp2f(fmaf(sc[qt][kt][0], C1, b4[0]));
                float p1 = __builtin_amdgcn_exp2f(fmaf(sc[qt][kt][1], C1, b4[1]));
                float p2 = __builtin_amdgcn_exp2f(fmaf(sc[qt][kt][2], C1, b4[2]));
                float p3 = __builtin_amdgcn_exp2f(fmaf(sc[qt][kt][3], C1, b4[3]));
                psum += (p0 + p1) + (p2 + p3);
                uint2 pk;
                pk.x = cvt_pk_bf16(p0, p1);
                pk.y = cvt_pk_bf16(p2, p3);
                int slot = kt * 2 + (lg >> 1);
                *reinterpret_cast<uint2*>(
                    &pw[((slot ^ rsw) * 8) + (lg & 1) * 4]) = pk;
            }
            psum += __shfl_xor(psum, 16);
            psum += __shfl_xor(psum, 32);
            lsum[qt] += psum;
        }

        // PV over this wave's key-half: oacc[qt][ct] += mfma(V^T, P)
        __builtin_amdgcn_s_setprio(1);
        #pragma unroll
        for (int kh = 0; kh < 2; ++kh) {
            int pslot = kh * 4 + lg;             // slot within 64-key half
            int vslot = kh2 * 8 + kh * 4 + lg;   // slot within 128-key tile
            short8 pf[2], vf[2];
            #pragma unroll
            for (int qt = 0; qt < 2; ++qt) {
                int prow = qt * 16 + l15;
                pf[qt] = *reinterpret_cast<const short8*>(
                    &ps[w][prow * 64 + ((pslot ^ (prow & 7)) * 8)]);
            }
            #pragma unroll
            for (int ct = 0; ct < 2; ++ct) {
                int crow = ct * 16 + l15;
                vf[ct] = *reinterpret_cast<const short8*>(
                    &vt[cur][crow * 128 + ((vslot ^ (crow & 7)) * 8)]);
            }
            #pragma unroll
            for (int qt = 0; qt < 2; ++qt)
                #pragma unroll
                for (int ct = 0; ct < 2; ++ct)
                    oacc[qt][ct] = __builtin_amdgcn_mfma_f32_16x16x32_bf16(
                        vf[ct], pf[qt], oacc[qt][ct], 0, 0, 0);
        }
        __builtin_amdgcn_s_setprio(0);

        if (more) {                      // write next chunk into other buffer
            int nxt = cur ^ 1;
            *reinterpret_cast<short8*>(&ksl[nxt][krow][kc8]) = kreg;
            #pragma unroll
            for (int j = 0; j < 4; ++j) {
                int c = cv + j;
                unsigned int pk = (unsigned int)(unsigned short)v0r[j] |
                                  ((unsigned int)(unsigned short)v1r[j] << 16);
                int slot = kp >> 2;
                int off  = c * 128 + ((slot ^ (c & 7)) * 8) + ((2 * kp) & 7);
                *reinterpret_cast<unsigned int*>(&vt[nxt][off]) = pk;
            }
            if (tid < 128) bias_s[nxt][tid] = breg;
        }
        __syncthreads();
    }

    // cross-half combine: odd waves park partials in ps (dead now), even
    // waves sum and finish (normalize, gate, bf16 store).
    float* scr = reinterpret_cast<float*>(&ps[0][0]);   // [4][64][18] floats
    if (kh2) {
        float* dst = scr + ((size_t)(qg * 64 + lane)) * 18;
        #pragma unroll
        for (int qt = 0; qt < 2; ++qt)
            #pragma unroll
            for (int ct = 0; ct < 2; ++ct)
                #pragma unroll
                for (int r = 0; r < 4; ++r)
                    dst[(qt * 2 + ct) * 4 + r] = oacc[qt][ct][r];
        dst[16] = lsum[0];
        dst[17] = lsum[1];
    }
    __syncthreads();
    if (!kh2) {
        const float* src = scr + ((size_t)(qg * 64 + lane)) * 18;
        #pragma unroll
        for (int qt = 0; qt < 2; ++qt)
            #pragma unroll
            for (int ct = 0; ct < 2; ++ct)
                #pragma unroll
                for (int r = 0; r < 4; ++r)
                    oacc[qt][ct][r] += src[(qt * 2 + ct) * 4 + r];
        lsum[0] += src[16];
        lsum[1] += src[17];

        #pragma unroll
        for (int qt = 0; qt < 2; ++qt) {
            float linv = 1.0f / lsum[qt];
            size_t base = ((size_t)(qrow0 + qt * 16 + l15) * 8 + b) * 256 + h * 32;
            #pragma unroll
            for (int ct = 0; ct < 2; ++ct) {
                int cc0 = ct * 16 + lg * 4;
                short4v g4 = *reinterpret_cast<const short4v*>(gb + base + cc0);
                float v0 = oacc[qt][ct][0] * linv * bf2f((unsigned short)g4[0]);
                float v1 = oacc[qt][ct][1] * linv * bf2f((unsigned short)g4[1]);
                float v2 = oacc[qt][ct][2] * linv * bf2f((unsigned short)g4[2]);
                float v3 = oacc[qt][ct][3] * linv * bf2f((unsigned short)g4[3]);
                uint2 st;
                st.x = cvt_pk_bf16(v0, v1);
                st.y = cvt_pk_bf16(v2, v3);
                *reinterpret_cast<uint2*>(ag + base + cc0) = st;
            }
        }
    }
}

// ---------------------------------------------------------------------------
// Final GEMM: out f32 = ag(bf16) @ Wo + bo. BM=64, BN=64 -> grid (128,4) =
// 512 blocks (2 blocks/CU, 8 waves/CU). global_load_lds staging,
// swapped operands -> float4 stores.
__global__ __launch_bounds__(256)
void gemm_out_kernel(const unsigned short* __restrict__ A,
                     const unsigned short* __restrict__ Bt,
                     const float* __restrict__ bias,
                     float* __restrict__ Cout) {
    __shared__ unsigned short Asb[64 * 64];
    __shared__ unsigned short Bsb[64 * 64];
    int tid  = threadIdx.x;
    int lane = tid & 63;
    int w    = tid >> 6;
    int l15  = lane & 15, lg = lane >> 4;
    int bm   = blockIdx.x * 64;
    int bn   = blockIdx.y * 64;

    float4v acc[4];
    #pragma unroll
    for (int i = 0; i < 4; ++i) acc[i] = (float4v){0.f, 0.f, 0.f, 0.f};

    for (int k0 = 0; k0 < 256; k0 += 64) {
        __syncthreads();
        #pragma unroll
        for (int j = 0; j < 2; ++j) {      // A: 8 chunks, 2 per wave
            int c = w * 2 + j;
            int u = c * 64 + lane;
            int row = u >> 3, slot = u & 7;
            gl_lds16(A + (size_t)(bm + row) * 256 + k0 + ((slot ^ (row & 7)) * 8),
                     Asb + c * 512);
        }
        #pragma unroll
        for (int j = 0; j < 2; ++j) {      // B: 8 chunks, 2 per wave
            int c = w * 2 + j;
            int u = c * 64 + lane;
            int row = u >> 3, slot = u & 7;
            gl_lds16(Bt + (size_t)(bn + row) * 256 + k0 + ((slot ^ (row & 7)) * 8),
                     Bsb + c * 512);
        }
        __syncthreads();
        #pragma unroll
        for (int kh = 0; kh < 2; ++kh) {
            int slot = kh * 4 + lg;
            short8 af[4], bf;
            #pragma unroll
            for (int mf = 0; mf < 4; ++mf) {
                int row = mf * 16 + l15;
                af[mf] = *reinterpret_cast<const short8*>(
                    Asb + row * 64 + ((slot ^ (row & 7)) * 8));
            }
            {
                int row = w * 16 + l15;
                bf = *reinterpret_cast<const short8*>(
                    Bsb + row * 64 + ((slot ^ (row & 7)) * 8));
            }
            #pragma unroll
            for (int mf = 0; mf < 4; ++mf)
                acc[mf] = __builtin_amdgcn_mfma_f32_16x16x32_bf16(
                    bf, af[mf], acc[mf], 0, 0, 0);  // D col = m-row
        }
    }
    int c0 = bn + w * 16 + lg * 4;
    float4 b4 = *reinterpret_cast<const float4*>(bias + c0);
    #pragma unroll
    for (int mf = 0; mf < 4; ++mf) {
        int m = bm + mf * 16 + l15;
        float4 o;
        o.x = acc[mf][0] + b4.x;
        o.y = acc[mf][1] + b4.y;
        o.z = acc[mf][2] + b4.z;
        o.w = acc[mf][3] + b4.w;
        *reinterpret_cast<float4*>(Cout + (size_t)m * 256 + c0) = o;
    }
}

// ---------------------------------------------------------------------------
extern "C" void kernel_launch(void* const* d_in, const int* in_sizes, int n_in,
                              void* d_out, int out_size, void* d_ws, size_t ws_size,
                              hipStream_t stream) {
    (void)in_sizes; (void)n_in; (void)out_size; (void)ws_size;
    const float* features = (const float*)d_in[0];
    const float* ln_g = (const float*)d_in[1];
    const float* ln_b = (const float*)d_in[2];
    const float* Wq = (const float*)d_in[3];
    const float* bq = (const float*)d_in[4];
    const float* Wk = (const float*)d_in[5];
    const float* bk = (const float*)d_in[6];
    const float* Wv = (const float*)d_in[7];
    const float* bv = (const float*)d_in[8];
    const float* Wb = (const float*)d_in[9];
    const float* bbv = (const float*)d_in[10];
    const float* Wg = (const float*)d_in[11];
    const float* bg = (const float*)d_in[12];
    const float* Wo = (const float*)d_in[13];
    const float* bo = (const float*)d_in[14];
    float* out = (float*)d_out;

    char* wsb = (char*)d_ws;
    unsigned short* xb    = (unsigned short*)(wsb);                   // 4 MB
    unsigned short* wt    = (unsigned short*)(wsb + 4194304);         // 512 KB
    unsigned short* wto   = (unsigned short*)(wsb + 4718592);         // 128 KB
    float*          bcomb = (float*)(wsb + 4849664);                  // 4 KB
    float*          wbt   = (float*)(wsb + 4853760);                  // 8 KB
    unsigned short* qkvg  = (unsigned short*)(wsb + 4861952);         // 16 MB
    float*          biasb = (float*)(wsb + 21639168);                 // 256 KB
    unsigned short* agb   = (unsigned short*)(wsb + 21901312);        // 4 MB

    prep_ln_kernel<<<dim3(2113), dim3(256), 0, stream>>>(
        features, ln_g, ln_b, Wq, Wk, Wv, Wg, Wo, Wb,
        bq, bk, bv, bg, xb, wt, wto, bcomb, wbt);
    qkvg_fused_kernel<<<dim3(768), dim3(256), 0, stream>>>(
        xb, wt, bcomb, wbt, bbv, qkvg, biasb);
    attn_mfma_kernel<<<dim3(8, 64), dim3(512), 0, stream>>>(
        qkvg, biasb, agb);
    gemm_out_kernel<<<dim3(128, 4), dim3(256), 0, stream>>>(
        agb, wto, bo, out);
}

// Round 15
// 58.447 us; speedup vs baseline: 1.0418x; 1.0418x over previous
//
#include <hip/hip_runtime.h>
#include <math.h>

#define LQ 1024
#define BB 8
#define FF 256
#define HH 8
#define CC 32
#define MROWS (LQ*BB)          // 8192
static constexpr float EPSV  = 1e-5f;
static constexpr float LOG2E = 1.4426950408889634f;
static constexpr float C1    = 0.17677669529663687f * 1.4426950408889634f; // (1/sqrt C)*log2e

typedef short  short8  __attribute__((ext_vector_type(8)));
typedef short  short4v __attribute__((ext_vector_type(4)));
typedef float  float4v __attribute__((ext_vector_type(4)));

__device__ inline unsigned short f2bf(float f) {   // RNE float->bf16
    unsigned int u = __builtin_bit_cast(unsigned int, f);
    u += 0x7FFFu + ((u >> 16) & 1u);
    return (unsigned short)(u >> 16);
}
__device__ inline float bf2f(unsigned short h) {
    unsigned int u = ((unsigned int)h) << 16;
    return __builtin_bit_cast(float, u);
}
__device__ inline unsigned int cvt_pk_bf16(float a, float b) {  // a->low16, b->high16
    unsigned int r;
    asm("v_cvt_pk_bf16_f32 %0, %1, %2" : "=v"(r) : "v"(a), "v"(b));
    return r;
}
// async global->LDS, 16B per lane; LDS dest = wave-uniform base + lane*16
__device__ __forceinline__ void gl_lds16(const unsigned short* g, unsigned short* l) {
    __builtin_amdgcn_global_load_lds(
        (const __attribute__((address_space(1))) void*)g,
        (__attribute__((address_space(3))) void*)l, 16, 0, 0);
}

// ---------------------------------------------------------------------------
// Fused prep: blocks 0..2047 LayerNorm+bf16 cast (4 rows each);
// blocks 2048..2111 transpose+cast weights; block 2112 transposes Wb.
__global__ __launch_bounds__(256)
void prep_ln_kernel(const float* __restrict__ x, const float* __restrict__ g,
                    const float* __restrict__ bln,
                    const float* __restrict__ Wq, const float* __restrict__ Wk,
                    const float* __restrict__ Wv, const float* __restrict__ Wg,
                    const float* __restrict__ Wo, const float* __restrict__ Wb,
                    const float* __restrict__ bq, const float* __restrict__ bk,
                    const float* __restrict__ bv, const float* __restrict__ bg,
                    unsigned short* __restrict__ xb, unsigned short* __restrict__ wt,
                    unsigned short* __restrict__ wto,
                    float* __restrict__ bcomb, float* __restrict__ wbt) {
    int bid = blockIdx.x;
    if (bid < 2048) {                      // LayerNorm path
        int wid  = threadIdx.x >> 6;
        int lane = threadIdx.x & 63;
        int row  = bid * 4 + wid;
        float4 v = reinterpret_cast<const float4*>(x + (size_t)row * FF)[lane];
        float s  = v.x + v.y + v.z + v.w;
        float sq = v.x*v.x + v.y*v.y + v.z*v.z + v.w*v.w;
        #pragma unroll
        for (int m = 1; m < 64; m <<= 1) {
            s  += __shfl_xor(s,  m);
            sq += __shfl_xor(sq, m);
        }
        float mean = s * (1.0f / FF);
        float var  = sq * (1.0f / FF) - mean * mean;
        float rstd = rsqrtf(var + EPSV);
        float4 gg = reinterpret_cast<const float4*>(g)[lane];
        float4 bv4 = reinterpret_cast<const float4*>(bln)[lane];
        short4v o;
        o[0] = (short)f2bf((v.x - mean) * rstd * gg.x + bv4.x);
        o[1] = (short)f2bf((v.y - mean) * rstd * gg.y + bv4.y);
        o[2] = (short)f2bf((v.z - mean) * rstd * gg.z + bv4.z);
        o[3] = (short)f2bf((v.w - mean) * rstd * gg.w + bv4.w);
        *reinterpret_cast<short4v*>(xb + (size_t)row * FF + lane * 4) = o;
    } else if (bid < 2112) {               // weight transpose path
        int k0 = (bid - 2048) * 4;
        int nl = threadIdx.x;
        const float* Ws[5] = {Wq, Wk, Wv, Wg, Wo};
        #pragma unroll
        for (int sel = 0; sel < 5; ++sel) {
            const float* W = Ws[sel];
            short4v o;
            #pragma unroll
            for (int j = 0; j < 4; ++j)
                o[j] = (short)f2bf(W[(size_t)(k0 + j) * 256 + nl]);
            unsigned short* dst = (sel < 4)
                ? (wt + ((size_t)sel * 256 + nl) * 256 + k0)
                : (wto + (size_t)nl * 256 + k0);
            *reinterpret_cast<short4v*>(dst) = o;
        }
        if (k0 == 0) {
            bcomb[nl]       = bq[nl];
            bcomb[256 + nl] = bk[nl];
            bcomb[512 + nl] = bv[nl];
            bcomb[768 + nl] = bg[nl];
        }
    } else {                               // Wb transpose: wbt[8][256] f32
        int nl = threadIdx.x;
        #pragma unroll
        for (int hh = 0; hh < 8; ++hh)
            wbt[hh * 256 + nl] = Wb[(size_t)nl * 8 + hh];
    }
}

// ---------------------------------------------------------------------------
// Fused QKVG projection GEMM (global_load_lds staging, pre-swizzled source)
// + bias projection. Blocks 0..511: GEMM 128x128; 512..767: biasproj.
__global__ __launch_bounds__(256)
void qkvg_fused_kernel(const unsigned short* __restrict__ A,
                       const unsigned short* __restrict__ Bt,
                       const float* __restrict__ bcomb,
                       const float* __restrict__ wbt,
                       const float* __restrict__ bbv,
                       unsigned short* __restrict__ outq,
                       float* __restrict__ outb) {
    __shared__ unsigned short Asb[128 * 64];
    __shared__ unsigned short Bsb[128 * 64];
    int bid = blockIdx.x;
    int tid = threadIdx.x;

    if (bid >= 512) {                      // bias projection path
        int idx = (bid - 512) * 256 + tid;
        int row = idx >> 3, hh = idx & 7;
        const unsigned short* xr = A + (size_t)row * 256;
        const float* wr = wbt + hh * 256;
        float s = 0.f;
        #pragma unroll 4
        for (int i = 0; i < 32; ++i) {
            short8 x8 = *reinterpret_cast<const short8*>(xr + i * 8);
            float4 wa = *reinterpret_cast<const float4*>(wr + i * 8);
            float4 wb2 = *reinterpret_cast<const float4*>(wr + i * 8 + 4);
            s += bf2f((unsigned short)x8[0]) * wa.x + bf2f((unsigned short)x8[1]) * wa.y
               + bf2f((unsigned short)x8[2]) * wa.z + bf2f((unsigned short)x8[3]) * wa.w;
            s += bf2f((unsigned short)x8[4]) * wb2.x + bf2f((unsigned short)x8[5]) * wb2.y
               + bf2f((unsigned short)x8[6]) * wb2.z + bf2f((unsigned short)x8[7]) * wb2.w;
        }
        outb[idx] = s + bbv[hh];
        return;
    }

    int lane = tid & 63;
    int w    = tid >> 6;
    int wm   = w >> 1, wn = w & 1;
    int l15  = lane & 15, lg = lane >> 4;
    int bm   = (bid & 63) * 128;
    int bn   = (bid >> 6) * 128;

    float4v acc[4][4];
    #pragma unroll
    for (int i = 0; i < 4; ++i)
        #pragma unroll
        for (int j = 0; j < 4; ++j)
            acc[i][j] = (float4v){0.f, 0.f, 0.f, 0.f};

    for (int k0 = 0; k0 < 256; k0 += 64) {
        __syncthreads();
        // each wave stages 4 chunks of A and 4 of B (chunk = 64 units = 1KB)
        #pragma unroll
        for (int j = 0; j < 4; ++j) {
            int c = w * 4 + j;
            int u = c * 64 + lane;
            int row = u >> 3, slot = u & 7;
            size_t gsw = (size_t)row * 256 + k0 + ((slot ^ (row & 7)) * 8);
            gl_lds16(A + (size_t)bm * 256 + gsw, Asb + c * 512);
            gl_lds16(Bt + (size_t)bn * 256 + gsw, Bsb + c * 512);
        }
        __syncthreads();
        #pragma unroll
        for (int kh = 0; kh < 2; ++kh) {
            int slot = kh * 4 + lg;
            short8 af[4], bf[4];
            #pragma unroll
            for (int mf = 0; mf < 4; ++mf) {
                int row = wm * 64 + mf * 16 + l15;
                af[mf] = *reinterpret_cast<const short8*>(
                    Asb + row * 64 + ((slot ^ (row & 7)) * 8));
            }
            #pragma unroll
            for (int nf = 0; nf < 4; ++nf) {
                int row = wn * 64 + nf * 16 + l15;
                bf[nf] = *reinterpret_cast<const short8*>(
                    Bsb + row * 64 + ((slot ^ (row & 7)) * 8));
            }
            #pragma unroll
            for (int mf = 0; mf < 4; ++mf)
                #pragma unroll
                for (int nf = 0; nf < 4; ++nf)
                    acc[mf][nf] = __builtin_amdgcn_mfma_f32_16x16x32_bf16(
                        bf[nf], af[mf], acc[mf][nf], 0, 0, 0);  // D col = m-row
        }
    }

    int sel = bn >> 8;
    unsigned short* outp = outq + (size_t)sel * MROWS * 256;
    #pragma unroll
    for (int mf = 0; mf < 4; ++mf) {
        int m = bm + wm * 64 + mf * 16 + l15;
        #pragma unroll
        for (int nf = 0; nf < 4; ++nf) {
            int nglob = bn + wn * 64 + nf * 16 + lg * 4;
            float4 b4 = *reinterpret_cast<const float4*>(bcomb + nglob);
            float v0 = acc[mf][nf][0] + b4.x;
            float v1 = acc[mf][nf][1] + b4.y;
            float v2 = acc[mf][nf][2] + b4.z;
            float v3 = acc[mf][nf][3] + b4.w;
            if (sel == 3) {
                v0 = 1.0f / (1.0f + __expf(-v0));
                v1 = 1.0f / (1.0f + __expf(-v1));
                v2 = 1.0f / (1.0f + __expf(-v2));
                v3 = 1.0f / (1.0f + __expf(-v3));
            }
            uint2 st;
            st.x = cvt_pk_bf16(v0, v1);
            st.y = cvt_pk_bf16(v2, v3);
            *reinterpret_cast<uint2*>(outp + (size_t)m * 256 + (nglob & 255)) = st;
        }
    }
}

// ---------------------------------------------------------------------------
// MFMA flash attention + gate, v8 (split-K). 512 thr = 8 waves; wave w owns
// q-group w>>1 (32 rows, 2 tiles) and key-half w&1 (64 of 128 keys).
// Per-wave LDS traffic drops 24->16 KB/chunk (K and V reads halve; kf reused
// across 2 q-tiles) at unchanged 16 waves/CU. No-max softmax => cross-half
// combine is a single end-of-kernel sum via the dead ps buffer.
__global__ __launch_bounds__(512)
void attn_mfma_kernel(const unsigned short* __restrict__ qkvg,
                      const float* __restrict__ biasp,
                      unsigned short* __restrict__ ag) {
    __shared__ unsigned short ksl[128][40];     // K chunk, stride 40 (2-way free)
    __shared__ unsigned short vt[32 * 128];     // V^T, 16-slot xor swizzle
    __shared__ unsigned short ps[8][32 * 64];   // per-wave P (32q x 64keys)
    __shared__ float bias_s[128];
    const unsigned short* qb = qkvg;
    const unsigned short* kb = qkvg + (size_t)MROWS * 256;
    const unsigned short* vb = qkvg + (size_t)MROWS * 256 * 2;
    const unsigned short* gb = qkvg + (size_t)MROWS * 256 * 3;

    int tid  = threadIdx.x;
    int lane = tid & 63;
    int w    = tid >> 6;                 // 0..7
    int l15  = lane & 15, lg = lane >> 4;
    int bh   = blockIdx.y;
    int b    = bh >> 3, h = bh & 7;
    int qg   = w >> 1;                   // q-group 0..3 (32 rows each)
    int kh2  = w & 1;                    // key-half 0/1 (64 keys each)
    int qrow0 = blockIdx.x * 128 + qg * 32;

    // staging assignment (all 512 threads stage full K and V^T)
    int krow = tid >> 2, kc8 = (tid & 3) * 8;        // K: 1 16B-unit each
    int cv = (tid & 7) * 4, kp = tid >> 3;           // V: keys 2kp,2kp+1, c cv..cv+3

    short8 qf[2];
    #pragma unroll
    for (int qt = 0; qt < 2; ++qt)
        qf[qt] = *reinterpret_cast<const short8*>(
            qb + ((size_t)(qrow0 + qt * 16 + l15) * 8 + b) * 256 + h * 32 + lg * 8);

    float lsum[2] = {0.f, 0.f};
    float4v oacc[2][2];
    #pragma unroll
    for (int i = 0; i < 2; ++i)
        #pragma unroll
        for (int j = 0; j < 2; ++j) oacc[i][j] = (float4v){0.f, 0.f, 0.f, 0.f};

    short8 kreg; short4v v0r, v1r; float breg = 0.f;
    {   // prefetch chunk 0
        kreg = *reinterpret_cast<const short8*>(
            kb + ((size_t)krow * 8 + b) * 256 + h * 32 + kc8);
        const unsigned short* vp =
            vb + ((size_t)(2 * kp) * 8 + b) * 256 + h * 32 + cv;
        v0r = *reinterpret_cast<const short4v*>(vp);
        v1r = *reinterpret_cast<const short4v*>(vp + 8 * 256);
        if (tid < 128) breg = biasp[(size_t)tid * 64 + b * 8 + h] * LOG2E;
    }

    for (int c0 = 0; c0 < LQ; c0 += 128) {
        __syncthreads();                 // prior compute done reading LDS
        *reinterpret_cast<short8*>(&ksl[krow][kc8]) = kreg;
        #pragma unroll
        for (int j = 0; j < 4; ++j) {
            int c = cv + j;
            unsigned int pk = (unsigned int)(unsigned short)v0r[j] |
                              ((unsigned int)(unsigned short)v1r[j] << 16);
            int slot = kp >> 2;
            int off  = c * 128 + ((slot ^ (c & 7)) * 8) + ((2 * kp) & 7);
            *reinterpret_cast<unsigned int*>(&vt[off]) = pk;
        }
        if (tid < 128) bias_s[tid] = breg;
        __syncthreads();
        int cn = c0 + 128;               // prefetch next chunk
        if (cn < LQ) {
            kreg = *reinterpret_cast<const short8*>(
                kb + ((size_t)(cn + krow) * 8 + b) * 256 + h * 32 + kc8);
            const unsigned short* vp =
                vb + ((size_t)(cn + 2 * kp) * 8 + b) * 256 + h * 32 + cv;
            v0r = *reinterpret_cast<const short4v*>(vp);
            v1r = *reinterpret_cast<const short4v*>(vp + 8 * 256);
            if (tid < 128) breg = biasp[(size_t)(cn + tid) * 64 + b * 8 + h] * LOG2E;
        }

        // S^T = mfma(K, Q) over this wave's key-half: key = kh2*64 + kt*16 +
        // lg*4 + r, col = q(l15). Each kf feeds both q-tiles (register reuse).
        __builtin_amdgcn_s_setprio(1);
        float4v sc[2][4];
        #pragma unroll
        for (int kt = 0; kt < 4; ++kt) {
            short8 kf = *reinterpret_cast<const short8*>(
                &ksl[kh2 * 64 + kt * 16 + l15][lg * 8]);
            #pragma unroll
            for (int qt = 0; qt < 2; ++qt)
                sc[qt][kt] = __builtin_amdgcn_mfma_f32_16x16x32_bf16(
                    kf, qf[qt], (float4v){0.f, 0.f, 0.f, 0.f}, 0, 0, 0);
        }
        __builtin_amdgcn_s_setprio(0);

        // P = exp2(qk*C1 + bias2), no max subtraction (|logit| small)
        #pragma unroll
        for (int qt = 0; qt < 2; ++qt) {
            int prow = qt * 16 + l15;
            unsigned short* pw = &ps[w][prow * 64];
            int rsw = prow & 7;
            float psum = 0.f;
            #pragma unroll
            for (int kt = 0; kt < 4; ++kt) {
                float4v b4 = *reinterpret_cast<const float4v*>(
                    &bias_s[kh2 * 64 + kt * 16 + lg * 4]);
                float p0 = __builtin_amdgcn_exp2f(fmaf(sc[qt][kt][0], C1, b4[0]));
                float p1 = __builtin_amdgcn_exp2f(fmaf(sc[qt][kt][1], C1, b4[1]));
                float p2 = __builtin_amdgcn_exp2f(fmaf(sc[qt][kt][2], C1, b4[2]));
                float p3 = __builtin_amdgcn_exp2f(fmaf(sc[qt][kt][3], C1, b4[3]));
                psum += (p0 + p1) + (p2 + p3);
                uint2 pk;
                pk.x = cvt_pk_bf16(p0, p1);
                pk.y = cvt_pk_bf16(p2, p3);
                int slot = kt * 2 + (lg >> 1);
                *reinterpret_cast<uint2*>(
                    &pw[((slot ^ rsw) * 8) + (lg & 1) * 4]) = pk;
            }
            psum += __shfl_xor(psum, 16);
            psum += __shfl_xor(psum, 32);
            lsum[qt] += psum;
        }

        // PV over this wave's key-half: oacc[qt][ct] += mfma(V^T, P)
        __builtin_amdgcn_s_setprio(1);
        #pragma unroll
        for (int kh = 0; kh < 2; ++kh) {
            int pslot = kh * 4 + lg;             // slot within 64-key half
            int vslot = kh2 * 8 + kh * 4 + lg;   // slot within 128-key tile
            short8 pf[2], vf[2];
            #pragma unroll
            for (int qt = 0; qt < 2; ++qt) {
                int prow = qt * 16 + l15;
                pf[qt] = *reinterpret_cast<const short8*>(
                    &ps[w][prow * 64 + ((pslot ^ (prow & 7)) * 8)]);
            }
            #pragma unroll
            for (int ct = 0; ct < 2; ++ct) {
                int crow = ct * 16 + l15;
                vf[ct] = *reinterpret_cast<const short8*>(
                    &vt[crow * 128 + ((vslot ^ (crow & 7)) * 8)]);
            }
            #pragma unroll
            for (int qt = 0; qt < 2; ++qt)
                #pragma unroll
                for (int ct = 0; ct < 2; ++ct)
                    oacc[qt][ct] = __builtin_amdgcn_mfma_f32_16x16x32_bf16(
                        vf[ct], pf[qt], oacc[qt][ct], 0, 0, 0);
        }
        __builtin_amdgcn_s_setprio(0);
    }

    // cross-half combine: odd waves park partials in ps (dead now), even
    // waves sum and finish (normalize, gate, bf16 store).
    __syncthreads();
    float* scr = reinterpret_cast<float*>(&ps[0][0]);   // [4][64][18] floats
    if (kh2) {
        float* dst = scr + ((size_t)(qg * 64 + lane)) * 18;
        #pragma unroll
        for (int qt = 0; qt < 2; ++qt)
            #pragma unroll
            for (int ct = 0; ct < 2; ++ct)
                #pragma unroll
                for (int r = 0; r < 4; ++r)
                    dst[(qt * 2 + ct) * 4 + r] = oacc[qt][ct][r];
        dst[16] = lsum[0];
        dst[17] = lsum[1];
    }
    __syncthreads();
    if (!kh2) {
        const float* src = scr + ((size_t)(qg * 64 + lane)) * 18;
        #pragma unroll
        for (int qt = 0; qt < 2; ++qt)
            #pragma unroll
            for (int ct = 0; ct < 2; ++ct)
                #pragma unroll
                for (int r = 0; r < 4; ++r)
                    oacc[qt][ct][r] += src[(qt * 2 + ct) * 4 + r];
        lsum[0] += src[16];
        lsum[1] += src[17];

        #pragma unroll
        for (int qt = 0; qt < 2; ++qt) {
            float linv = 1.0f / lsum[qt];
            size_t base = ((size_t)(qrow0 + qt * 16 + l15) * 8 + b) * 256 + h * 32;
            #pragma unroll
            for (int ct = 0; ct < 2; ++ct) {
                int cc0 = ct * 16 + lg * 4;
                short4v g4 = *reinterpret_cast<const short4v*>(gb + base + cc0);
                float v0 = oacc[qt][ct][0] * linv * bf2f((unsigned short)g4[0]);
                float v1 = oacc[qt][ct][1] * linv * bf2f((unsigned short)g4[1]);
                float v2 = oacc[qt][ct][2] * linv * bf2f((unsigned short)g4[2]);
                float v3 = oacc[qt][ct][3] * linv * bf2f((unsigned short)g4[3]);
                uint2 st;
                st.x = cvt_pk_bf16(v0, v1);
                st.y = cvt_pk_bf16(v2, v3);
                *reinterpret_cast<uint2*>(ag + base + cc0) = st;
            }
        }
    }
}

// ---------------------------------------------------------------------------
// Final GEMM: out f32 = ag(bf16) @ Wo + bo. BM=64, BN=64 -> grid (128,4) =
// 512 blocks (2 blocks/CU, 8 waves/CU). global_load_lds staging,
// swapped operands -> float4 stores.
__global__ __launch_bounds__(256)
void gemm_out_kernel(const unsigned short* __restrict__ A,
                     const unsigned short* __restrict__ Bt,
                     const float* __restrict__ bias,
                     float* __restrict__ Cout) {
    __shared__ unsigned short Asb[64 * 64];
    __shared__ unsigned short Bsb[64 * 64];
    int tid  = threadIdx.x;
    int lane = tid & 63;
    int w    = tid >> 6;
    int l15  = lane & 15, lg = lane >> 4;
    int bm   = blockIdx.x * 64;
    int bn   = blockIdx.y * 64;

    float4v acc[4];
    #pragma unroll
    for (int i = 0; i < 4; ++i) acc[i] = (float4v){0.f, 0.f, 0.f, 0.f};

    for (int k0 = 0; k0 < 256; k0 += 64) {
        __syncthreads();
        #pragma unroll
        for (int j = 0; j < 2; ++j) {      // A: 8 chunks, 2 per wave
            int c = w * 2 + j;
            int u = c * 64 + lane;
            int row = u >> 3, slot = u & 7;
            gl_lds16(A + (size_t)(bm + row) * 256 + k0 + ((slot ^ (row & 7)) * 8),
                     Asb + c * 512);
        }
        #pragma unroll
        for (int j = 0; j < 2; ++j) {      // B: 8 chunks, 2 per wave
            int c = w * 2 + j;
            int u = c * 64 + lane;
            int row = u >> 3, slot = u & 7;
            gl_lds16(Bt + (size_t)(bn + row) * 256 + k0 + ((slot ^ (row & 7)) * 8),
                     Bsb + c * 512);
        }
        __syncthreads();
        #pragma unroll
        for (int kh = 0; kh < 2; ++kh) {
            int slot = kh * 4 + lg;
            short8 af[4], bf;
            #pragma unroll
            for (int mf = 0; mf < 4; ++mf) {
                int row = mf * 16 + l15;
                af[mf] = *reinterpret_cast<const short8*>(
                    Asb + row * 64 + ((slot ^ (row & 7)) * 8));
            }
            {
                int row = w * 16 + l15;
                bf = *reinterpret_cast<const short8*>(
                    Bsb + row * 64 + ((slot ^ (row & 7)) * 8));
            }
            #pragma unroll
            for (int mf = 0; mf < 4; ++mf)
                acc[mf] = __builtin_amdgcn_mfma_f32_16x16x32_bf16(
                    bf, af[mf], acc[mf], 0, 0, 0);  // D col = m-row
        }
    }
    int c0 = bn + w * 16 + lg * 4;
    float4 b4 = *reinterpret_cast<const float4*>(bias + c0);
    #pragma unroll
    for (int mf = 0; mf < 4; ++mf) {
        int m = bm + mf * 16 + l15;
        float4 o;
        o.x = acc[mf][0] + b4.x;
        o.y = acc[mf][1] + b4.y;
        o.z = acc[mf][2] + b4.z;
        o.w = acc[mf][3] + b4.w;
        *reinterpret_cast<float4*>(Cout + (size_t)m * 256 + c0) = o;
    }
}

// ---------------------------------------------------------------------------
extern "C" void kernel_launch(void* const* d_in, const int* in_sizes, int n_in,
                              void* d_out, int out_size, void* d_ws, size_t ws_size,
                              hipStream_t stream) {
    (void)in_sizes; (void)n_in; (void)out_size; (void)ws_size;
    const float* features = (const float*)d_in[0];
    const float* ln_g = (const float*)d_in[1];
    const float* ln_b = (const float*)d_in[2];
    const float* Wq = (const float*)d_in[3];
    const float* bq = (const float*)d_in[4];
    const float* Wk = (const float*)d_in[5];
    const float* bk = (const float*)d_in[6];
    const float* Wv = (const float*)d_in[7];
    const float* bv = (const float*)d_in[8];
    const float* Wb = (const float*)d_in[9];
    const float* bbv = (const float*)d_in[10];
    const float* Wg = (const float*)d_in[11];
    const float* bg = (const float*)d_in[12];
    const float* Wo = (const float*)d_in[13];
    const float* bo = (const float*)d_in[14];
    float* out = (float*)d_out;

    char* wsb = (char*)d_ws;
    unsigned short* xb    = (unsigned short*)(wsb);                   // 4 MB
    unsigned short* wt    = (unsigned short*)(wsb + 4194304);         // 512 KB
    unsigned short* wto   = (unsigned short*)(wsb + 4718592);         // 128 KB
    float*          bcomb = (float*)(wsb + 4849664);                  // 4 KB
    float*          wbt   = (float*)(wsb + 4853760);                  // 8 KB
    unsigned short* qkvg  = (unsigned short*)(wsb + 4861952);         // 16 MB
    float*          biasb = (float*)(wsb + 21639168);                 // 256 KB
    unsigned short* agb   = (unsigned short*)(wsb + 21901312);        // 4 MB

    prep_ln_kernel<<<dim3(2113), dim3(256), 0, stream>>>(
        features, ln_g, ln_b, Wq, Wk, Wv, Wg, Wo, Wb,
        bq, bk, bv, bg, xb, wt, wto, bcomb, wbt);
    qkvg_fused_kernel<<<dim3(768), dim3(256), 0, stream>>>(
        xb, wt, bcomb, wbt, bbv, qkvg, biasb);
    attn_mfma_kernel<<<dim3(8, 64), dim3(512), 0, stream>>>(
        qkvg, biasb, agb);
    gemm_out_kernel<<<dim3(128, 4), dim3(256), 0, stream>>>(
        agb, wto, bo, out);
}